// Round 10
// baseline (285.336 us; speedup 1.0000x reference)
//
#include <hip/hip_runtime.h>
#include <stdint.h>

#define TT 48
#define HH 180
#define WW 240
#define KCAP 4
#define HWPIX (HH*WW)                   // 43200
#define NSLOTS ((size_t)TT*HWPIX*KCAP)  // 8294400
#define CAP 16384
#define TS_STEP 33333
#define NCHUNK 169                      // ceil(43200/256)
#define STILE 2048                      // sorted-tile size
#define SPAD(i) ((i) + ((i) >> 4) + ((i) >> 8))   // LDS anti-bank-conflict pad for bitonic strides

// ---------------- Kernel 1a: pure serial ref chain per pixel — no atomics/barriers/LDS ----------------
__global__ void ref_scan(const float* __restrict__ images, float* __restrict__ refs,
                         uint8_t* __restrict__ npol) {
#pragma clang fp contract(off)
  int p = blockIdx.x * 256 + threadIdx.x;
  if (p >= HWPIX) return;
  float ref = images[p];                         // init_ref = images[0]
  npol[p] = 0;                                   // t=0: diff==0 exactly -> ni=0, pol=0
  refs[p] = ref;                                 // refs[0] = init_ref
  float cur = images[(size_t)HWPIX + p];         // 2-deep prefetch
  float nxt = images[(size_t)2 * HWPIX + p];
  for (int t = 1; t < TT; ++t) {
    float img = cur;
    cur = nxt;
    if (t + 2 < TT) nxt = images[(size_t)(t + 2) * HWPIX + p];
    float diff = img - ref;
    float pol = (diff > 0.0f) ? 1.0f : ((diff < 0.0f) ? -1.0f : 0.0f);
    float n = floorf(fabsf(diff) / 0.2f);        // IEEE float div, matches jnp
    int ni = (int)n;
    int pc = (pol > 0.0f) ? 1 : ((pol < 0.0f) ? 2 : 0);
    npol[(size_t)t * HWPIX + p] = (uint8_t)(ni | (pc << 3));
    float nct = n * 0.2f;
    ref = ref + pol * nct;                       // new_ref (no FMA)
    refs[(size_t)t * HWPIX + p] = ref;
  }
}

// ---------------- Kernel 1b: event emission + fused per-chunk prefix scan ----------------
// grid (NCHUNK, TT). Emits events (LDS-aggregated slot reservation, 3 near-buckets) AND computes
// the chunk-local exclusive prefix of event counts + chunk totals (wave shuffle scan) in the same
// barrier structure. t=0 blocks have ni==0 everywhere (npol[0]=0) -> scan-only.
__global__ void event_emit(const float* __restrict__ images, const float* __restrict__ refs,
                           const uint8_t* __restrict__ npol, uint32_t* __restrict__ bucket_count,
                           uint64_t* __restrict__ keys, uint32_t* __restrict__ meta,
                           uint32_t* __restrict__ pixpre, uint32_t* __restrict__ chunk_sum) {
#pragma clang fp contract(off)
  __shared__ uint32_t lcnt[3];
  __shared__ uint32_t gbase[3];
  __shared__ uint32_t wsum[4];
  int t = blockIdx.y;                            // t in [0, TT)
  int tid = threadIdx.x;
  int p = blockIdx.x * 256 + tid;
  if (tid < 3) lcnt[tid] = 0;
  __syncthreads();

  int ni = 0;
  uint64_t ek[KCAP]; uint32_t em[KCAP]; uint32_t eli[KCAP]; uint32_t esl[KCAP]; int eb[KCAP];

  if (p < HWPIX) {
    uint8_t bb = npol[(size_t)t * HWPIX + p];
    ni = bb & 7;                                 // 0 for t==0
    if (ni > 0) {
      int pc = (bb >> 3) & 3;
      float pol = (pc == 1) ? 1.0f : ((pc == 2) ? -1.0f : 0.0f);
      float ref = refs[(size_t)(t - 1) * HWPIX + p];        // ref BEFORE frame t
      float img_prev = images[(size_t)(t - 1) * HWPIX + p];
      float img = images[(size_t)t * HWPIX + p];
      float denom = img - img_prev;
      double tsprev = (double)((t - 1) * TS_STEP);          // exact
      double delta = (double)TS_STEP;                       // exact
#pragma unroll
      for (int k = 1; k <= KCAP; ++k) {
        if (k <= ni) {
          float kct = (float)k * 0.2f;
          float v = ref + pol * kct;             // crossed level (no FMA)
          float qv = v - img_prev;
          float frac = (denom == 0.0f) ? 0.0f : (qv / denom);
          double t_ev = tsprev + (double)frac * delta;      // no FMA

          // bucket by VALUE: first b with ts[b-1] < t_ev <= ts[b]; frac can be << 0!
          int b = t;
          while (b > 0 && t_ev <= (double)((b - 1) * TS_STEP)) --b;
          while (b < TT - 1 && t_ev > (double)(b * TS_STEP)) ++b;

          uint64_t ub = (uint64_t)__double_as_longlong(t_ev);
          uint64_t key = (ub & 0x8000000000000000ULL) ? ~ub : (ub ^ 0x8000000000000000ULL);
          uint32_t gidx = (((uint32_t)t * HWPIX + (uint32_t)p) << 2) + (uint32_t)(k - 1);
          ek[k - 1] = key;
          em[k - 1] = gidx | ((pol < 0.0f ? 1u : 0u) << 23);
          eb[k - 1] = b;
          int li = b - (t - 1);
          if (li >= 0 && li <= 2) {
            eli[k - 1] = (uint32_t)li;
            esl[k - 1] = atomicAdd(&lcnt[li], 1u);            // LDS atomic
          } else {
            eli[k - 1] = 3u;                                   // rare far-bucket fallback
            esl[k - 1] = atomicAdd(&bucket_count[b], 1u);      // per-event global atomic
          }
        }
      }
    }
  }

  // fused chunk scan: wave shuffle scan of ni over the 256-thread block
  uint32_t v = (uint32_t)ni;
  uint32_t lane = (uint32_t)(tid & 63);
  int w = tid >> 6;
  uint32_t x = v;
#pragma unroll
  for (int d = 1; d < 64; d <<= 1) {
    uint32_t y = __shfl_up(x, d, 64);
    if (lane >= (uint32_t)d) x += y;
  }
  if (lane == 63) wsum[w] = x;
  __syncthreads();                               // covers lcnt finalize AND wsum

  uint32_t wb = 0;
#pragma unroll
  for (int j = 0; j < 4; ++j) if (j < w) wb += wsum[j];
  uint32_t incl = x + wb;
  if (p < HWPIX) pixpre[(size_t)t * HWPIX + p] = incl - v;   // chunk-local exclusive prefix
  if (tid == 255) chunk_sum[t * NCHUNK + blockIdx.x] = incl; // chunk total

  if (tid < 3) {                                 // one global atomic per (block, near-bucket)
    int b = t - 1 + tid;
    uint32_t c = lcnt[tid];
    uint32_t g = 0;
    if (c > 0 && b >= 0 && b < TT) g = atomicAdd(&bucket_count[b], c);
    gbase[tid] = g;
  }
  __syncthreads();

#pragma unroll
  for (int k = 0; k < KCAP; ++k) {
    if (k < ni) {
      uint32_t li = eli[k];
      uint32_t s = (li == 3u) ? esl[k] : (gbase[li] + esl[k]);
      if (s < CAP) {
        keys[(size_t)eb[k] * CAP + s] = ek[k];
        meta[(size_t)eb[k] * CAP + s] = em[k];
      }
    }
  }
}

// ---------------- Kernel 2b: per-frame scan of 169 chunk totals -> chunk_base, frame_total ----------------
__global__ void chunk_base_scan(const uint32_t* __restrict__ chunk_sum, uint32_t* __restrict__ chunk_base,
                                uint32_t* __restrict__ frame_total) {
  int f = blockIdx.x;
  int tid = threadIdx.x;
  uint32_t v = (tid < NCHUNK) ? chunk_sum[f * NCHUNK + tid] : 0u;
  uint32_t lane = (uint32_t)(tid & 63);
  int w = tid >> 6;
  uint32_t x = v;
#pragma unroll
  for (int d = 1; d < 64; d <<= 1) {
    uint32_t y = __shfl_up(x, d, 64);
    if (lane >= (uint32_t)d) x += y;
  }
  __shared__ uint32_t wsum[4];
  if (lane == 63) wsum[w] = x;
  __syncthreads();
  uint32_t wb = 0;
#pragma unroll
  for (int j = 0; j < 4; ++j) if (j < w) wb += wsum[j];
  uint32_t incl = x + wb;
  if (tid < NCHUNK) chunk_base[f * NCHUNK + tid] = incl - v;  // exclusive prefix of chunk sums
  if (tid == 255) frame_total[f] = incl;                      // frame total
}

// ---------------- Kernel 3: tiny serial scans (48 elements each) ----------------
__global__ void small_scans(const uint32_t* __restrict__ bucket_count, uint32_t* __restrict__ bucket_base,
                            const uint32_t* __restrict__ frame_total, uint32_t* __restrict__ frame_base) {
  if (threadIdx.x == 0 && blockIdx.x == 0) {
    uint32_t s = 0;
    for (int i = 0; i < TT; ++i) {
      bucket_base[i] = s;
      uint32_t c = bucket_count[i]; if (c > CAP) c = CAP;
      s += c;
    }
    bucket_base[TT] = s;
    s = 0;
    for (int i = 0; i < TT; ++i) { frame_base[i] = s; s += frame_total[i]; }
    frame_base[TT] = s;
  }
}

// ---------------- Kernel 4a: bitonic-sort each 2048-element tile of each bucket in-place (by key, tie gidx) ----------------
__global__ void sort_tiles(uint64_t* __restrict__ keys, uint32_t* __restrict__ meta,
                           const uint32_t* __restrict__ bucket_count) {
  int b = blockIdx.y;
  uint32_t m = bucket_count[b]; if (m > CAP) m = CAP;
  uint32_t tile0 = blockIdx.x * STILE;
  if (tile0 >= m) return;
  __shared__ uint64_t sk[2184];
  __shared__ uint32_t sm[2184];
  int tid = threadIdx.x;
#pragma unroll
  for (int r = 0; r < 8; ++r) {
    uint32_t i = (uint32_t)(r * 256 + tid);
    uint32_t e = tile0 + i;
    bool have = e < m;
    sk[SPAD(i)] = have ? keys[(size_t)b * CAP + e] : ~0ULL;    // sentinel > any real key
    sm[SPAD(i)] = have ? meta[(size_t)b * CAP + e] : 0x7FFFFFu;
  }
  __syncthreads();
  for (uint32_t kk = 2; kk <= STILE; kk <<= 1) {
    for (uint32_t j = kk >> 1; j > 0; j >>= 1) {
#pragma unroll 4
      for (int r = 0; r < 4; ++r) {
        uint32_t idx = (uint32_t)(r * 256 + tid);
        uint32_t i1 = ((idx & ~(j - 1u)) << 1) | (idx & (j - 1u));
        uint32_t i2 = i1 + j;
        uint32_t p1 = SPAD(i1), p2 = SPAD(i2);
        uint64_t ka = sk[p1], kb2 = sk[p2];
        uint32_t ma = sm[p1], mb = sm[p2];
        bool agt = (ka > kb2) || (ka == kb2 && (ma & 0x7FFFFFu) > (mb & 0x7FFFFFu));
        bool desc = (i1 & kk) != 0;
        if (agt != desc) { sk[p1] = kb2; sk[p2] = ka; sm[p1] = mb; sm[p2] = ma; }
      }
      __syncthreads();
    }
  }
#pragma unroll
  for (int r = 0; r < 8; ++r) {
    uint32_t i = (uint32_t)(r * 256 + tid);
    uint32_t e = tile0 + i;                    // e < CAP always (CAP multiple of STILE)
    keys[(size_t)b * CAP + e] = sk[SPAD(i)];
    meta[(size_t)b * CAP + e] = sm[SPAD(i)];
  }
}

// ---------------- Kernel 4b: rank + scatter — one block OWNS a whole 2048-tile (8 elems/thread) ----------------
// Stages each OTHER tile once (8x less staging than per-256 blocks); 8 independent branchless
// 12-probe lower_bounds advance in lockstep per probe-width -> ILP hides LDS latency.
__global__ void rank_scatter(const uint64_t* __restrict__ keys, const uint32_t* __restrict__ meta,
                             const uint32_t* __restrict__ bucket_count, const uint32_t* __restrict__ bucket_base,
                             int32_t* __restrict__ out) {
  int b = blockIdx.y;
  uint32_t m = bucket_count[b]; if (m > CAP) m = CAP;
  uint32_t own = blockIdx.x;
  uint32_t tile0 = own * STILE;
  if (tile0 >= m) return;
  uint32_t ntiles = (m + STILE - 1u) / STILE;
  __shared__ uint64_t sk[STILE];
  __shared__ uint32_t sm[STILE];
  int tid = threadIdx.x;

  uint64_t myk[8]; uint32_t mym[8]; uint32_t rank[8];
#pragma unroll
  for (int r = 0; r < 8; ++r) {
    uint32_t i = (uint32_t)(r * 256 + tid);
    uint32_t e = tile0 + i;
    bool have = e < m;
    myk[r] = have ? keys[(size_t)b * CAP + e] : ~0ULL;
    mym[r] = have ? meta[(size_t)b * CAP + e] : 0x7FFFFFu;
    rank[r] = i;                                 // own sorted tile: rank = in-tile position
  }

  for (uint32_t t2 = 0; t2 < ntiles; ++t2) {
    if (t2 == own) continue;                     // block-uniform skip
#pragma unroll
    for (int r = 0; r < 8; ++r) {
      uint32_t i = (uint32_t)(r * 256 + tid);
      uint32_t j = t2 * STILE + i;
      sk[i] = (j < m) ? keys[(size_t)b * CAP + j] : ~0ULL;
      sm[i] = (j < m) ? meta[(size_t)b * CAP + j] : 0x7FFFFFu;
    }
    __syncthreads();
    uint32_t pos[8];
#pragma unroll
    for (int r = 0; r < 8; ++r) pos[r] = 0;
#pragma unroll
    for (uint32_t w2 = STILE >> 1; w2 > 0; w2 >>= 1) {   // 11 probe rounds, 8 searches in lockstep
#pragma unroll
      for (int r = 0; r < 8; ++r) {
        uint32_t idx = pos[r] + w2 - 1u;
        uint64_t kj = sk[idx];
        uint32_t ij = sm[idx] & 0x7FFFFFu;
        bool less = (kj < myk[r]) || (kj == myk[r] && ij < (mym[r] & 0x7FFFFFu));
        if (less) pos[r] += w2;
      }
    }
#pragma unroll
    for (int r = 0; r < 8; ++r) {                // 12th probe: final correction, pos in [0, STILE]
      uint64_t kj = sk[pos[r]];
      uint32_t ij = sm[pos[r]] & 0x7FFFFFu;
      bool less = (kj < myk[r]) || (kj == myk[r] && ij < (mym[r] & 0x7FFFFFu));
      rank[r] += pos[r] + (less ? 1u : 0u);
    }
    __syncthreads();
  }

  uint32_t bb0 = bucket_base[b];
#pragma unroll
  for (int r = 0; r < 8; ++r) {
    uint32_t e = tile0 + (uint32_t)(r * 256 + tid);
    if (e < m) {
      uint32_t pos = bb0 + rank[r];
      uint64_t ub = (myk[r] & 0x8000000000000000ULL) ? (myk[r] ^ 0x8000000000000000ULL) : ~myk[r];
      double t_ev = __longlong_as_double((long long)ub);
      uint32_t myidx = mym[r] & 0x7FFFFFu;
      uint32_t pix = (myidx >> 2) % HWPIX;
      uint32_t x = pix % WW, y = pix / WW;
      int32_t pval = ((mym[r] >> 23) & 1u) ? -1 : 1;
      long long ti = (long long)t_ev;           // trunc-toward-zero == astype(int64) for t_ev >= 0
      out[pos]              = (int32_t)x;
      out[NSLOTS + pos]     = (int32_t)y;
      out[2 * NSLOTS + pos] = (int32_t)ti;
      out[3 * NSLOTS + pos] = pval;
      out[4 * NSLOTS + pos] = 1;
    }
  }
}

// ---------------- Kernel 5: invalid slots -> tail, original flat order ----------------
__global__ void invalid_scatter(const uint8_t* __restrict__ npol, const uint32_t* __restrict__ pixpre,
                                const uint32_t* __restrict__ chunk_base, const uint32_t* __restrict__ frame_base,
                                int32_t* __restrict__ out) {
  uint32_t s = blockIdx.x * blockDim.x + threadIdx.x;
  if (s >= (uint32_t)NSLOTS) return;
  uint32_t k = (s & 3u) + 1u;
  uint32_t tp = s >> 2;
  uint32_t t = tp / HWPIX;
  uint32_t pix = tp - t * HWPIX;
  uint8_t bb = npol[tp];
  uint32_t n = bb & 7u;
  if (k <= n) return;                          // valid slot, handled by rank_scatter
  uint32_t nvalid_total = frame_base[TT];
  uint32_t vb = frame_base[t] + chunk_base[t * NCHUNK + (pix >> 8)] + pixpre[tp] + min(k - 1u, n);
  uint32_t pos = nvalid_total + (s - vb);
  uint32_t x = pix % WW, y = pix / WW;
  uint32_t pc = (bb >> 3) & 3u;
  int32_t pval = (pc == 1u) ? 1 : ((pc == 2u) ? -1 : 0);
  out[pos]              = (int32_t)x;
  out[NSLOTS + pos]     = (int32_t)y;
  out[2 * NSLOTS + pos] = 0;
  out[3 * NSLOTS + pos] = pval;
  out[4 * NSLOTS + pos] = 0;
}

extern "C" void kernel_launch(void* const* d_in, const int* in_sizes, int n_in,
                              void* d_out, int out_size, void* d_ws, size_t ws_size,
                              hipStream_t stream) {
  const float* images = (const float*)d_in[0];
  int32_t* out = (int32_t*)d_out;

  uint8_t* base = (uint8_t*)d_ws;
  size_t off = 0;
  auto carve = [&](size_t bytes, size_t align) -> void* {
    off = (off + align - 1) & ~(align - 1);
    void* p = base + off; off += bytes; return p;
  };
  uint32_t* bucket_count = (uint32_t*)carve(TT * 4, 256);
  uint32_t* bucket_base  = (uint32_t*)carve((TT + 1) * 4, 256);
  uint32_t* frame_total  = (uint32_t*)carve(TT * 4, 256);
  uint32_t* frame_base   = (uint32_t*)carve((TT + 1) * 4, 256);
  uint8_t*  npol         = (uint8_t*) carve((size_t)TT * HWPIX, 256);
  float*    refs         = (float*)   carve((size_t)TT * HWPIX * 4, 256);
  uint32_t* pixpre       = (uint32_t*)carve((size_t)TT * HWPIX * 4, 256);
  uint32_t* chunk_sum    = (uint32_t*)carve((size_t)TT * NCHUNK * 4, 256);
  uint32_t* chunk_base   = (uint32_t*)carve((size_t)TT * NCHUNK * 4, 256);
  uint64_t* keys         = (uint64_t*)carve((size_t)TT * CAP * 8, 256);
  uint32_t* meta         = (uint32_t*)carve((size_t)TT * CAP * 4, 256);
  (void)ws_size; (void)out_size; (void)in_sizes; (void)n_in;

  hipMemsetAsync(bucket_count, 0, TT * 4, stream);
  ref_scan<<<(HWPIX + 255) / 256, 256, 0, stream>>>(images, refs, npol);
  dim3 ge(NCHUNK, TT);
  event_emit<<<ge, 256, 0, stream>>>(images, refs, npol, bucket_count, keys, meta, pixpre, chunk_sum);
  chunk_base_scan<<<TT, 256, 0, stream>>>(chunk_sum, chunk_base, frame_total);
  small_scans<<<1, 64, 0, stream>>>(bucket_count, bucket_base, frame_total, frame_base);
  dim3 gs(CAP / STILE, TT);
  sort_tiles<<<gs, 256, 0, stream>>>(keys, meta, bucket_count);
  rank_scatter<<<gs, 256, 0, stream>>>(keys, meta, bucket_count, bucket_base, out);
  invalid_scatter<<<(uint32_t)((NSLOTS + 255) / 256), 256, 0, stream>>>(npol, pixpre, chunk_base, frame_base, out);
}

// Round 11
// 255.692 us; speedup vs baseline: 1.1159x; 1.1159x over previous
//
#include <hip/hip_runtime.h>
#include <stdint.h>

#define TT 48
#define HH 180
#define WW 240
#define KCAP 4
#define HWPIX (HH*WW)                   // 43200
#define NSLOTS ((size_t)TT*HWPIX*KCAP)  // 8294400
#define CAP 16384
#define TS_STEP 33333
#define NCHUNK 169                      // ceil(43200/256)
#define STILE 2048                      // sorted-tile size
#define SPAD(i) ((i) + ((i) >> 4) + ((i) >> 8))   // LDS anti-bank-conflict pad for bitonic strides

// ---------------- Kernel 1a: pure serial ref chain per pixel — no atomics/barriers/LDS ----------------
__global__ void ref_scan(const float* __restrict__ images, float* __restrict__ refs,
                         uint8_t* __restrict__ npol) {
#pragma clang fp contract(off)
  int p = blockIdx.x * 256 + threadIdx.x;
  if (p >= HWPIX) return;
  float ref = images[p];                         // init_ref = images[0]
  npol[p] = 0;                                   // t=0: diff==0 exactly -> ni=0, pol=0
  refs[p] = ref;                                 // refs[0] = init_ref
  float cur = images[(size_t)HWPIX + p];         // 2-deep prefetch
  float nxt = images[(size_t)2 * HWPIX + p];
  for (int t = 1; t < TT; ++t) {
    float img = cur;
    cur = nxt;
    if (t + 2 < TT) nxt = images[(size_t)(t + 2) * HWPIX + p];
    float diff = img - ref;
    float pol = (diff > 0.0f) ? 1.0f : ((diff < 0.0f) ? -1.0f : 0.0f);
    float n = floorf(fabsf(diff) / 0.2f);        // IEEE float div, matches jnp
    int ni = (int)n;
    int pc = (pol > 0.0f) ? 1 : ((pol < 0.0f) ? 2 : 0);
    npol[(size_t)t * HWPIX + p] = (uint8_t)(ni | (pc << 3));
    float nct = n * 0.2f;
    ref = ref + pol * nct;                       // new_ref (no FMA)
    refs[(size_t)t * HWPIX + p] = ref;
  }
}

// ---------------- Kernel 1b: event emission + fused per-chunk prefix scan ----------------
__global__ void event_emit(const float* __restrict__ images, const float* __restrict__ refs,
                           const uint8_t* __restrict__ npol, uint32_t* __restrict__ bucket_count,
                           uint64_t* __restrict__ keys, uint32_t* __restrict__ meta,
                           uint32_t* __restrict__ pixpre, uint32_t* __restrict__ chunk_sum) {
#pragma clang fp contract(off)
  __shared__ uint32_t lcnt[3];
  __shared__ uint32_t gbase[3];
  __shared__ uint32_t wsum[4];
  int t = blockIdx.y;                            // t in [0, TT)
  int tid = threadIdx.x;
  int p = blockIdx.x * 256 + tid;
  if (tid < 3) lcnt[tid] = 0;
  __syncthreads();

  int ni = 0;
  uint64_t ek[KCAP]; uint32_t em[KCAP]; uint32_t eli[KCAP]; uint32_t esl[KCAP]; int eb[KCAP];

  if (p < HWPIX) {
    uint8_t bb = npol[(size_t)t * HWPIX + p];
    ni = bb & 7;                                 // 0 for t==0
    if (ni > 0) {
      int pc = (bb >> 3) & 3;
      float pol = (pc == 1) ? 1.0f : ((pc == 2) ? -1.0f : 0.0f);
      float ref = refs[(size_t)(t - 1) * HWPIX + p];        // ref BEFORE frame t
      float img_prev = images[(size_t)(t - 1) * HWPIX + p];
      float img = images[(size_t)t * HWPIX + p];
      float denom = img - img_prev;
      double tsprev = (double)((t - 1) * TS_STEP);          // exact
      double delta = (double)TS_STEP;                       // exact
#pragma unroll
      for (int k = 1; k <= KCAP; ++k) {
        if (k <= ni) {
          float kct = (float)k * 0.2f;
          float v = ref + pol * kct;             // crossed level (no FMA)
          float qv = v - img_prev;
          float frac = (denom == 0.0f) ? 0.0f : (qv / denom);
          double t_ev = tsprev + (double)frac * delta;      // no FMA

          // bucket by VALUE: first b with ts[b-1] < t_ev <= ts[b]; frac can be << 0!
          int b = t;
          while (b > 0 && t_ev <= (double)((b - 1) * TS_STEP)) --b;
          while (b < TT - 1 && t_ev > (double)(b * TS_STEP)) ++b;

          uint64_t ub = (uint64_t)__double_as_longlong(t_ev);
          uint64_t key = (ub & 0x8000000000000000ULL) ? ~ub : (ub ^ 0x8000000000000000ULL);
          uint32_t gidx = (((uint32_t)t * HWPIX + (uint32_t)p) << 2) + (uint32_t)(k - 1);
          ek[k - 1] = key;
          em[k - 1] = gidx | ((pol < 0.0f ? 1u : 0u) << 23);
          eb[k - 1] = b;
          int li = b - (t - 1);
          if (li >= 0 && li <= 2) {
            eli[k - 1] = (uint32_t)li;
            esl[k - 1] = atomicAdd(&lcnt[li], 1u);            // LDS atomic
          } else {
            eli[k - 1] = 3u;                                   // rare far-bucket fallback
            esl[k - 1] = atomicAdd(&bucket_count[b], 1u);      // per-event global atomic
          }
        }
      }
    }
  }

  // fused chunk scan: wave shuffle scan of ni over the 256-thread block
  uint32_t v = (uint32_t)ni;
  uint32_t lane = (uint32_t)(tid & 63);
  int w = tid >> 6;
  uint32_t x = v;
#pragma unroll
  for (int d = 1; d < 64; d <<= 1) {
    uint32_t y = __shfl_up(x, d, 64);
    if (lane >= (uint32_t)d) x += y;
  }
  if (lane == 63) wsum[w] = x;
  __syncthreads();                               // covers lcnt finalize AND wsum

  uint32_t wb = 0;
#pragma unroll
  for (int j = 0; j < 4; ++j) if (j < w) wb += wsum[j];
  uint32_t incl = x + wb;
  if (p < HWPIX) pixpre[(size_t)t * HWPIX + p] = incl - v;   // chunk-local exclusive prefix
  if (tid == 255) chunk_sum[t * NCHUNK + blockIdx.x] = incl; // chunk total

  if (tid < 3) {                                 // one global atomic per (block, near-bucket)
    int b = t - 1 + tid;
    uint32_t c = lcnt[tid];
    uint32_t g = 0;
    if (c > 0 && b >= 0 && b < TT) g = atomicAdd(&bucket_count[b], c);
    gbase[tid] = g;
  }
  __syncthreads();

#pragma unroll
  for (int k = 0; k < KCAP; ++k) {
    if (k < ni) {
      uint32_t li = eli[k];
      uint32_t s = (li == 3u) ? esl[k] : (gbase[li] + esl[k]);
      if (s < CAP) {
        keys[(size_t)eb[k] * CAP + s] = ek[k];
        meta[(size_t)eb[k] * CAP + s] = em[k];
      }
    }
  }
}

// ---------------- Kernel 2b: per-frame scan of 169 chunk totals -> chunk_base, frame_total ----------------
__global__ void chunk_base_scan(const uint32_t* __restrict__ chunk_sum, uint32_t* __restrict__ chunk_base,
                                uint32_t* __restrict__ frame_total) {
  int f = blockIdx.x;
  int tid = threadIdx.x;
  uint32_t v = (tid < NCHUNK) ? chunk_sum[f * NCHUNK + tid] : 0u;
  uint32_t lane = (uint32_t)(tid & 63);
  int w = tid >> 6;
  uint32_t x = v;
#pragma unroll
  for (int d = 1; d < 64; d <<= 1) {
    uint32_t y = __shfl_up(x, d, 64);
    if (lane >= (uint32_t)d) x += y;
  }
  __shared__ uint32_t wsum[4];
  if (lane == 63) wsum[w] = x;
  __syncthreads();
  uint32_t wb = 0;
#pragma unroll
  for (int j = 0; j < 4; ++j) if (j < w) wb += wsum[j];
  uint32_t incl = x + wb;
  if (tid < NCHUNK) chunk_base[f * NCHUNK + tid] = incl - v;  // exclusive prefix of chunk sums
  if (tid == 255) frame_total[f] = incl;                      // frame total
}

// ---------------- Kernel 3: tiny serial scans (48 elements each) ----------------
__global__ void small_scans(const uint32_t* __restrict__ bucket_count, uint32_t* __restrict__ bucket_base,
                            const uint32_t* __restrict__ frame_total, uint32_t* __restrict__ frame_base) {
  if (threadIdx.x == 0 && blockIdx.x == 0) {
    uint32_t s = 0;
    for (int i = 0; i < TT; ++i) {
      bucket_base[i] = s;
      uint32_t c = bucket_count[i]; if (c > CAP) c = CAP;
      s += c;
    }
    bucket_base[TT] = s;
    s = 0;
    for (int i = 0; i < TT; ++i) { frame_base[i] = s; s += frame_total[i]; }
    frame_base[TT] = s;
  }
}

// ---------------- Kernel 4a: bitonic-sort each 2048-element tile of each bucket in-place (by key, tie gidx) ----------------
__global__ void sort_tiles(uint64_t* __restrict__ keys, uint32_t* __restrict__ meta,
                           const uint32_t* __restrict__ bucket_count) {
  int b = blockIdx.y;
  uint32_t m = bucket_count[b]; if (m > CAP) m = CAP;
  uint32_t tile0 = blockIdx.x * STILE;
  if (tile0 >= m) return;
  __shared__ uint64_t sk[2184];
  __shared__ uint32_t sm[2184];
  int tid = threadIdx.x;
#pragma unroll
  for (int r = 0; r < 8; ++r) {
    uint32_t i = (uint32_t)(r * 256 + tid);
    uint32_t e = tile0 + i;
    bool have = e < m;
    sk[SPAD(i)] = have ? keys[(size_t)b * CAP + e] : ~0ULL;    // sentinel > any real key
    sm[SPAD(i)] = have ? meta[(size_t)b * CAP + e] : 0x7FFFFFu;
  }
  __syncthreads();
  for (uint32_t kk = 2; kk <= STILE; kk <<= 1) {
    for (uint32_t j = kk >> 1; j > 0; j >>= 1) {
#pragma unroll 4
      for (int r = 0; r < 4; ++r) {
        uint32_t idx = (uint32_t)(r * 256 + tid);
        uint32_t i1 = ((idx & ~(j - 1u)) << 1) | (idx & (j - 1u));
        uint32_t i2 = i1 + j;
        uint32_t p1 = SPAD(i1), p2 = SPAD(i2);
        uint64_t ka = sk[p1], kb2 = sk[p2];
        uint32_t ma = sm[p1], mb = sm[p2];
        bool agt = (ka > kb2) || (ka == kb2 && (ma & 0x7FFFFFu) > (mb & 0x7FFFFFu));
        bool desc = (i1 & kk) != 0;
        if (agt != desc) { sk[p1] = kb2; sk[p2] = ka; sm[p1] = mb; sm[p2] = ma; }
      }
      __syncthreads();
    }
  }
#pragma unroll
  for (int r = 0; r < 8; ++r) {
    uint32_t i = (uint32_t)(r * 256 + tid);
    uint32_t e = tile0 + i;                    // e < CAP always (CAP multiple of STILE)
    keys[(size_t)b * CAP + e] = sk[SPAD(i)];
    meta[(size_t)b * CAP + e] = sm[SPAD(i)];
  }
}

// ---------------- Kernel 4b: pair-parallel cross-tile partial ranks ----------------
// grid (8 own-tiles x 8 other-tiles, TT). Each block stages ONE other-tile (once per pair) and
// lower_bounds its own tile's 2048 elements against it; partial ranks accumulate via atomicAdd
// (integer sum, commutative -> deterministic). Diagonal pairs exit (in-tile rank added at scatter).
__global__ void rank_pairs(const uint64_t* __restrict__ keys, const uint32_t* __restrict__ meta,
                           const uint32_t* __restrict__ bucket_count, uint32_t* __restrict__ rank_arr) {
  int b = blockIdx.y;
  uint32_t m = bucket_count[b]; if (m > CAP) m = CAP;
  uint32_t own = blockIdx.x >> 3, oth = blockIdx.x & 7u;
  if (own == oth) return;
  uint32_t tile0 = own * STILE;
  uint32_t oth0 = oth * STILE;
  if (tile0 >= m || oth0 >= m) return;
  __shared__ uint64_t sk[STILE];
  __shared__ uint32_t sm[STILE];
  int tid = threadIdx.x;
#pragma unroll
  for (int r = 0; r < 8; ++r) {
    uint32_t i = (uint32_t)(r * 256 + tid);
    uint32_t j = oth0 + i;
    sk[i] = (j < m) ? keys[(size_t)b * CAP + j] : ~0ULL;
    sm[i] = (j < m) ? meta[(size_t)b * CAP + j] : 0x7FFFFFu;
  }
  __syncthreads();

  uint64_t myk[8]; uint32_t mym[8];
#pragma unroll
  for (int r = 0; r < 8; ++r) {
    uint32_t e = tile0 + (uint32_t)(r * 256 + tid);
    bool have = e < m;
    myk[r] = have ? keys[(size_t)b * CAP + e] : ~0ULL;
    mym[r] = have ? meta[(size_t)b * CAP + e] : 0x7FFFFFu;
  }
  uint32_t pos[8];
#pragma unroll
  for (int r = 0; r < 8; ++r) pos[r] = 0;
#pragma unroll
  for (uint32_t w2 = STILE >> 1; w2 > 0; w2 >>= 1) {   // 11 probe rounds, 8 searches in lockstep
#pragma unroll
    for (int r = 0; r < 8; ++r) {
      uint32_t idx = pos[r] + w2 - 1u;
      uint64_t kj = sk[idx];
      uint32_t ij = sm[idx] & 0x7FFFFFu;
      bool less = (kj < myk[r]) || (kj == myk[r] && ij < (mym[r] & 0x7FFFFFu));
      if (less) pos[r] += w2;
    }
  }
#pragma unroll
  for (int r = 0; r < 8; ++r) {                // final correction probe; contrib in [0, STILE]
    uint32_t e = tile0 + (uint32_t)(r * 256 + tid);
    uint64_t kj = sk[pos[r]];
    uint32_t ij = sm[pos[r]] & 0x7FFFFFu;
    bool less = (kj < myk[r]) || (kj == myk[r] && ij < (mym[r] & 0x7FFFFFu));
    uint32_t contrib = pos[r] + (less ? 1u : 0u);
    if (e < m && contrib) atomicAdd(&rank_arr[(size_t)b * CAP + e], contrib);
  }
}

// ---------------- Kernel 4c: scatter valid events using accumulated ranks ----------------
__global__ void scatter_valid(const uint64_t* __restrict__ keys, const uint32_t* __restrict__ meta,
                              const uint32_t* __restrict__ bucket_count, const uint32_t* __restrict__ bucket_base,
                              const uint32_t* __restrict__ rank_arr, int32_t* __restrict__ out) {
  int b = blockIdx.y;
  uint32_t m = bucket_count[b]; if (m > CAP) m = CAP;
  uint32_t e = blockIdx.x * 256u + threadIdx.x;
  if (e >= m) return;
  uint64_t myk = keys[(size_t)b * CAP + e];
  uint32_t mym = meta[(size_t)b * CAP + e];
  uint32_t rank = rank_arr[(size_t)b * CAP + e] + (e & (STILE - 1u));  // cross-tile + in-tile
  uint32_t pos = bucket_base[b] + rank;
  uint64_t ub = (myk & 0x8000000000000000ULL) ? (myk ^ 0x8000000000000000ULL) : ~myk;
  double t_ev = __longlong_as_double((long long)ub);
  uint32_t myidx = mym & 0x7FFFFFu;
  uint32_t pix = (myidx >> 2) % HWPIX;
  uint32_t x = pix % WW, y = pix / WW;
  int32_t pval = ((mym >> 23) & 1u) ? -1 : 1;
  long long ti = (long long)t_ev;              // trunc-toward-zero == astype(int64) for t_ev >= 0
  out[pos]              = (int32_t)x;
  out[NSLOTS + pos]     = (int32_t)y;
  out[2 * NSLOTS + pos] = (int32_t)ti;
  out[3 * NSLOTS + pos] = pval;
  out[4 * NSLOTS + pos] = 1;
}

// ---------------- Kernel 5: invalid slots -> tail, original flat order ----------------
__global__ void invalid_scatter(const uint8_t* __restrict__ npol, const uint32_t* __restrict__ pixpre,
                                const uint32_t* __restrict__ chunk_base, const uint32_t* __restrict__ frame_base,
                                int32_t* __restrict__ out) {
  uint32_t s = blockIdx.x * blockDim.x + threadIdx.x;
  if (s >= (uint32_t)NSLOTS) return;
  uint32_t k = (s & 3u) + 1u;
  uint32_t tp = s >> 2;
  uint32_t t = tp / HWPIX;
  uint32_t pix = tp - t * HWPIX;
  uint8_t bb = npol[tp];
  uint32_t n = bb & 7u;
  if (k <= n) return;                          // valid slot, handled by scatter_valid
  uint32_t nvalid_total = frame_base[TT];
  uint32_t vb = frame_base[t] + chunk_base[t * NCHUNK + (pix >> 8)] + pixpre[tp] + min(k - 1u, n);
  uint32_t pos = nvalid_total + (s - vb);
  uint32_t x = pix % WW, y = pix / WW;
  uint32_t pc = (bb >> 3) & 3u;
  int32_t pval = (pc == 1u) ? 1 : ((pc == 2u) ? -1 : 0);
  out[pos]              = (int32_t)x;
  out[NSLOTS + pos]     = (int32_t)y;
  out[2 * NSLOTS + pos] = 0;
  out[3 * NSLOTS + pos] = pval;
  out[4 * NSLOTS + pos] = 0;
}

extern "C" void kernel_launch(void* const* d_in, const int* in_sizes, int n_in,
                              void* d_out, int out_size, void* d_ws, size_t ws_size,
                              hipStream_t stream) {
  const float* images = (const float*)d_in[0];
  int32_t* out = (int32_t*)d_out;

  uint8_t* base = (uint8_t*)d_ws;
  size_t off = 0;
  auto carve = [&](size_t bytes, size_t align) -> void* {
    off = (off + align - 1) & ~(align - 1);
    void* p = base + off; off += bytes; return p;
  };
  uint32_t* bucket_count = (uint32_t*)carve(TT * 4, 256);
  uint32_t* bucket_base  = (uint32_t*)carve((TT + 1) * 4, 256);
  uint32_t* frame_total  = (uint32_t*)carve(TT * 4, 256);
  uint32_t* frame_base   = (uint32_t*)carve((TT + 1) * 4, 256);
  uint8_t*  npol         = (uint8_t*) carve((size_t)TT * HWPIX, 256);
  float*    refs         = (float*)   carve((size_t)TT * HWPIX * 4, 256);
  uint32_t* pixpre       = (uint32_t*)carve((size_t)TT * HWPIX * 4, 256);
  uint32_t* chunk_sum    = (uint32_t*)carve((size_t)TT * NCHUNK * 4, 256);
  uint32_t* chunk_base   = (uint32_t*)carve((size_t)TT * NCHUNK * 4, 256);
  uint64_t* keys         = (uint64_t*)carve((size_t)TT * CAP * 8, 256);
  uint32_t* meta         = (uint32_t*)carve((size_t)TT * CAP * 4, 256);
  uint32_t* rank_arr     = (uint32_t*)carve((size_t)TT * CAP * 4, 256);
  (void)ws_size; (void)out_size; (void)in_sizes; (void)n_in;

  hipMemsetAsync(bucket_count, 0, TT * 4, stream);
  hipMemsetAsync(rank_arr, 0, (size_t)TT * CAP * 4, stream);
  ref_scan<<<(HWPIX + 255) / 256, 256, 0, stream>>>(images, refs, npol);
  dim3 ge(NCHUNK, TT);
  event_emit<<<ge, 256, 0, stream>>>(images, refs, npol, bucket_count, keys, meta, pixpre, chunk_sum);
  chunk_base_scan<<<TT, 256, 0, stream>>>(chunk_sum, chunk_base, frame_total);
  small_scans<<<1, 64, 0, stream>>>(bucket_count, bucket_base, frame_total, frame_base);
  dim3 gs(CAP / STILE, TT);
  sort_tiles<<<gs, 256, 0, stream>>>(keys, meta, bucket_count);
  dim3 gp(64, TT);
  rank_pairs<<<gp, 256, 0, stream>>>(keys, meta, bucket_count, rank_arr);
  dim3 gv(CAP / 256, TT);
  scatter_valid<<<gv, 256, 0, stream>>>(keys, meta, bucket_count, bucket_base, rank_arr, out);
  invalid_scatter<<<(uint32_t)((NSLOTS + 255) / 256), 256, 0, stream>>>(npol, pixpre, chunk_base, frame_base, out);
}

// Round 12
// 248.330 us; speedup vs baseline: 1.1490x; 1.0296x over previous
//
#include <hip/hip_runtime.h>
#include <stdint.h>

#define TT 48
#define HH 180
#define WW 240
#define KCAP 4
#define HWPIX (HH*WW)                   // 43200
#define NSLOTS ((size_t)TT*HWPIX*KCAP)  // 8294400
#define CAP 16384
#define TS_STEP 33333
#define NCHUNK 169                      // ceil(43200/256)
#define STILE 2048                      // sorted-tile size
#define SPAD(i) ((i) + ((i) >> 4) + ((i) >> 8))   // LDS anti-bank-conflict pad for bitonic strides

// ---------------- Kernel 1a: pure serial ref chain per pixel — also zeroes bucket_count ----------------
__global__ void ref_scan(const float* __restrict__ images, float* __restrict__ refs,
                         uint8_t* __restrict__ npol, uint32_t* __restrict__ bucket_count) {
#pragma clang fp contract(off)
  if (blockIdx.x == 0 && threadIdx.x < TT) bucket_count[threadIdx.x] = 0;   // replaces hipMemsetAsync
  int p = blockIdx.x * 256 + threadIdx.x;
  if (p >= HWPIX) return;
  float ref = images[p];                         // init_ref = images[0]
  npol[p] = 0;                                   // t=0: diff==0 exactly -> ni=0, pol=0
  refs[p] = ref;                                 // refs[0] = init_ref
  float cur = images[(size_t)HWPIX + p];         // 2-deep prefetch
  float nxt = images[(size_t)2 * HWPIX + p];
  for (int t = 1; t < TT; ++t) {
    float img = cur;
    cur = nxt;
    if (t + 2 < TT) nxt = images[(size_t)(t + 2) * HWPIX + p];
    float diff = img - ref;
    float pol = (diff > 0.0f) ? 1.0f : ((diff < 0.0f) ? -1.0f : 0.0f);
    float n = floorf(fabsf(diff) / 0.2f);        // IEEE float div, matches jnp
    int ni = (int)n;
    int pc = (pol > 0.0f) ? 1 : ((pol < 0.0f) ? 2 : 0);
    npol[(size_t)t * HWPIX + p] = (uint8_t)(ni | (pc << 3));
    float nct = n * 0.2f;
    ref = ref + pol * nct;                       // new_ref (no FMA)
    refs[(size_t)t * HWPIX + p] = ref;
  }
}

// ---------------- Kernel 1b: event emission + fused per-chunk prefix scan ----------------
__global__ void event_emit(const float* __restrict__ images, const float* __restrict__ refs,
                           const uint8_t* __restrict__ npol, uint32_t* __restrict__ bucket_count,
                           uint64_t* __restrict__ keys, uint32_t* __restrict__ meta,
                           uint32_t* __restrict__ pixpre, uint32_t* __restrict__ chunk_sum) {
#pragma clang fp contract(off)
  __shared__ uint32_t lcnt[3];
  __shared__ uint32_t gbase[3];
  __shared__ uint32_t wsum[4];
  int t = blockIdx.y;                            // t in [0, TT)
  int tid = threadIdx.x;
  int p = blockIdx.x * 256 + tid;
  if (tid < 3) lcnt[tid] = 0;
  __syncthreads();

  int ni = 0;
  uint64_t ek[KCAP]; uint32_t em[KCAP]; uint32_t eli[KCAP]; uint32_t esl[KCAP]; int eb[KCAP];

  if (p < HWPIX) {
    uint8_t bb = npol[(size_t)t * HWPIX + p];
    ni = bb & 7;                                 // 0 for t==0
    if (ni > 0) {
      int pc = (bb >> 3) & 3;
      float pol = (pc == 1) ? 1.0f : ((pc == 2) ? -1.0f : 0.0f);
      float ref = refs[(size_t)(t - 1) * HWPIX + p];        // ref BEFORE frame t
      float img_prev = images[(size_t)(t - 1) * HWPIX + p];
      float img = images[(size_t)t * HWPIX + p];
      float denom = img - img_prev;
      double tsprev = (double)((t - 1) * TS_STEP);          // exact
      double delta = (double)TS_STEP;                       // exact
#pragma unroll
      for (int k = 1; k <= KCAP; ++k) {
        if (k <= ni) {
          float kct = (float)k * 0.2f;
          float v = ref + pol * kct;             // crossed level (no FMA)
          float qv = v - img_prev;
          float frac = (denom == 0.0f) ? 0.0f : (qv / denom);
          double t_ev = tsprev + (double)frac * delta;      // no FMA

          // bucket by VALUE: first b with ts[b-1] < t_ev <= ts[b]; frac can be << 0!
          int b = t;
          while (b > 0 && t_ev <= (double)((b - 1) * TS_STEP)) --b;
          while (b < TT - 1 && t_ev > (double)(b * TS_STEP)) ++b;

          uint64_t ub = (uint64_t)__double_as_longlong(t_ev);
          uint64_t key = (ub & 0x8000000000000000ULL) ? ~ub : (ub ^ 0x8000000000000000ULL);
          uint32_t gidx = (((uint32_t)t * HWPIX + (uint32_t)p) << 2) + (uint32_t)(k - 1);
          ek[k - 1] = key;
          em[k - 1] = gidx | ((pol < 0.0f ? 1u : 0u) << 23);
          eb[k - 1] = b;
          int li = b - (t - 1);
          if (li >= 0 && li <= 2) {
            eli[k - 1] = (uint32_t)li;
            esl[k - 1] = atomicAdd(&lcnt[li], 1u);            // LDS atomic
          } else {
            eli[k - 1] = 3u;                                   // rare far-bucket fallback
            esl[k - 1] = atomicAdd(&bucket_count[b], 1u);      // per-event global atomic
          }
        }
      }
    }
  }

  // fused chunk scan: wave shuffle scan of ni over the 256-thread block
  uint32_t v = (uint32_t)ni;
  uint32_t lane = (uint32_t)(tid & 63);
  int w = tid >> 6;
  uint32_t x = v;
#pragma unroll
  for (int d = 1; d < 64; d <<= 1) {
    uint32_t y = __shfl_up(x, d, 64);
    if (lane >= (uint32_t)d) x += y;
  }
  if (lane == 63) wsum[w] = x;
  __syncthreads();                               // covers lcnt finalize AND wsum

  uint32_t wb = 0;
#pragma unroll
  for (int j = 0; j < 4; ++j) if (j < w) wb += wsum[j];
  uint32_t incl = x + wb;
  if (p < HWPIX) pixpre[(size_t)t * HWPIX + p] = incl - v;   // chunk-local exclusive prefix
  if (tid == 255) chunk_sum[t * NCHUNK + blockIdx.x] = incl; // chunk total

  if (tid < 3) {                                 // one global atomic per (block, near-bucket)
    int b = t - 1 + tid;
    uint32_t c = lcnt[tid];
    uint32_t g = 0;
    if (c > 0 && b >= 0 && b < TT) g = atomicAdd(&bucket_count[b], c);
    gbase[tid] = g;
  }
  __syncthreads();

#pragma unroll
  for (int k = 0; k < KCAP; ++k) {
    if (k < ni) {
      uint32_t li = eli[k];
      uint32_t s = (li == 3u) ? esl[k] : (gbase[li] + esl[k]);
      if (s < CAP) {
        keys[(size_t)eb[k] * CAP + s] = ek[k];
        meta[(size_t)eb[k] * CAP + s] = em[k];
      }
    }
  }
}

// ---------------- Kernel 2b: per-frame scan of 169 chunk totals -> chunk_base, frame_total ----------------
__global__ void chunk_base_scan(const uint32_t* __restrict__ chunk_sum, uint32_t* __restrict__ chunk_base,
                                uint32_t* __restrict__ frame_total) {
  int f = blockIdx.x;
  int tid = threadIdx.x;
  uint32_t v = (tid < NCHUNK) ? chunk_sum[f * NCHUNK + tid] : 0u;
  uint32_t lane = (uint32_t)(tid & 63);
  int w = tid >> 6;
  uint32_t x = v;
#pragma unroll
  for (int d = 1; d < 64; d <<= 1) {
    uint32_t y = __shfl_up(x, d, 64);
    if (lane >= (uint32_t)d) x += y;
  }
  __shared__ uint32_t wsum[4];
  if (lane == 63) wsum[w] = x;
  __syncthreads();
  uint32_t wb = 0;
#pragma unroll
  for (int j = 0; j < 4; ++j) if (j < w) wb += wsum[j];
  uint32_t incl = x + wb;
  if (tid < NCHUNK) chunk_base[f * NCHUNK + tid] = incl - v;  // exclusive prefix of chunk sums
  if (tid == 255) frame_total[f] = incl;                      // frame total
}

// ---------------- Kernel 3: tiny serial scans (48 elements each) ----------------
__global__ void small_scans(const uint32_t* __restrict__ bucket_count, uint32_t* __restrict__ bucket_base,
                            const uint32_t* __restrict__ frame_total, uint32_t* __restrict__ frame_base) {
  if (threadIdx.x == 0 && blockIdx.x == 0) {
    uint32_t s = 0;
    for (int i = 0; i < TT; ++i) {
      bucket_base[i] = s;
      uint32_t c = bucket_count[i]; if (c > CAP) c = CAP;
      s += c;
    }
    bucket_base[TT] = s;
    s = 0;
    for (int i = 0; i < TT; ++i) { frame_base[i] = s; s += frame_total[i]; }
    frame_base[TT] = s;
  }
}

// ---------------- Kernel 4a: bitonic-sort each 2048-tile in-place; also zeroes rank_arr for its tile ----------------
__global__ void sort_tiles(uint64_t* __restrict__ keys, uint32_t* __restrict__ meta,
                           const uint32_t* __restrict__ bucket_count, uint32_t* __restrict__ rank_arr) {
  int b = blockIdx.y;
  uint32_t m = bucket_count[b]; if (m > CAP) m = CAP;
  uint32_t tile0 = blockIdx.x * STILE;
  if (tile0 >= m) return;
  __shared__ uint64_t sk[2184];
  __shared__ uint32_t sm[2184];
  int tid = threadIdx.x;
#pragma unroll
  for (int r = 0; r < 8; ++r) {
    uint32_t i = (uint32_t)(r * 256 + tid);
    uint32_t e = tile0 + i;
    bool have = e < m;
    sk[SPAD(i)] = have ? keys[(size_t)b * CAP + e] : ~0ULL;    // sentinel > any real key
    sm[SPAD(i)] = have ? meta[(size_t)b * CAP + e] : 0x7FFFFFu;
    rank_arr[(size_t)b * CAP + e] = 0;           // replaces hipMemsetAsync(rank_arr)
  }
  __syncthreads();
  for (uint32_t kk = 2; kk <= STILE; kk <<= 1) {
    for (uint32_t j = kk >> 1; j > 0; j >>= 1) {
#pragma unroll 4
      for (int r = 0; r < 4; ++r) {
        uint32_t idx = (uint32_t)(r * 256 + tid);
        uint32_t i1 = ((idx & ~(j - 1u)) << 1) | (idx & (j - 1u));
        uint32_t i2 = i1 + j;
        uint32_t p1 = SPAD(i1), p2 = SPAD(i2);
        uint64_t ka = sk[p1], kb2 = sk[p2];
        uint32_t ma = sm[p1], mb = sm[p2];
        bool agt = (ka > kb2) || (ka == kb2 && (ma & 0x7FFFFFu) > (mb & 0x7FFFFFu));
        bool desc = (i1 & kk) != 0;
        if (agt != desc) { sk[p1] = kb2; sk[p2] = ka; sm[p1] = mb; sm[p2] = ma; }
      }
      __syncthreads();
    }
  }
#pragma unroll
  for (int r = 0; r < 8; ++r) {
    uint32_t i = (uint32_t)(r * 256 + tid);
    uint32_t e = tile0 + i;                    // e < CAP always (CAP multiple of STILE)
    keys[(size_t)b * CAP + e] = sk[SPAD(i)];
    meta[(size_t)b * CAP + e] = sm[SPAD(i)];
  }
}

// ---------------- Kernel 4b: pair-parallel cross-tile partial ranks ----------------
__global__ void rank_pairs(const uint64_t* __restrict__ keys, const uint32_t* __restrict__ meta,
                           const uint32_t* __restrict__ bucket_count, uint32_t* __restrict__ rank_arr) {
  int b = blockIdx.y;
  uint32_t m = bucket_count[b]; if (m > CAP) m = CAP;
  uint32_t own = blockIdx.x >> 3, oth = blockIdx.x & 7u;
  if (own == oth) return;
  uint32_t tile0 = own * STILE;
  uint32_t oth0 = oth * STILE;
  if (tile0 >= m || oth0 >= m) return;
  __shared__ uint64_t sk[STILE];
  __shared__ uint32_t sm[STILE];
  int tid = threadIdx.x;
#pragma unroll
  for (int r = 0; r < 8; ++r) {
    uint32_t i = (uint32_t)(r * 256 + tid);
    uint32_t j = oth0 + i;
    sk[i] = (j < m) ? keys[(size_t)b * CAP + j] : ~0ULL;
    sm[i] = (j < m) ? meta[(size_t)b * CAP + j] : 0x7FFFFFu;
  }
  __syncthreads();

  uint64_t myk[8]; uint32_t mym[8];
#pragma unroll
  for (int r = 0; r < 8; ++r) {
    uint32_t e = tile0 + (uint32_t)(r * 256 + tid);
    bool have = e < m;
    myk[r] = have ? keys[(size_t)b * CAP + e] : ~0ULL;
    mym[r] = have ? meta[(size_t)b * CAP + e] : 0x7FFFFFu;
  }
  uint32_t pos[8];
#pragma unroll
  for (int r = 0; r < 8; ++r) pos[r] = 0;
#pragma unroll
  for (uint32_t w2 = STILE >> 1; w2 > 0; w2 >>= 1) {   // 11 probe rounds, 8 searches in lockstep
#pragma unroll
    for (int r = 0; r < 8; ++r) {
      uint32_t idx = pos[r] + w2 - 1u;
      uint64_t kj = sk[idx];
      uint32_t ij = sm[idx] & 0x7FFFFFu;
      bool less = (kj < myk[r]) || (kj == myk[r] && ij < (mym[r] & 0x7FFFFFu));
      if (less) pos[r] += w2;
    }
  }
#pragma unroll
  for (int r = 0; r < 8; ++r) {                // final correction probe; contrib in [0, STILE]
    uint32_t e = tile0 + (uint32_t)(r * 256 + tid);
    uint64_t kj = sk[pos[r]];
    uint32_t ij = sm[pos[r]] & 0x7FFFFFu;
    bool less = (kj < myk[r]) || (kj == myk[r] && ij < (mym[r] & 0x7FFFFFu));
    uint32_t contrib = pos[r] + (less ? 1u : 0u);
    if (e < m && contrib) atomicAdd(&rank_arr[(size_t)b * CAP + e], contrib);
  }
}

// ---------------- Kernel 4c: scatter valid events using accumulated ranks ----------------
__global__ void scatter_valid(const uint64_t* __restrict__ keys, const uint32_t* __restrict__ meta,
                              const uint32_t* __restrict__ bucket_count, const uint32_t* __restrict__ bucket_base,
                              const uint32_t* __restrict__ rank_arr, int32_t* __restrict__ out) {
  int b = blockIdx.y;
  uint32_t m = bucket_count[b]; if (m > CAP) m = CAP;
  uint32_t e = blockIdx.x * 256u + threadIdx.x;
  if (e >= m) return;
  uint64_t myk = keys[(size_t)b * CAP + e];
  uint32_t mym = meta[(size_t)b * CAP + e];
  uint32_t rank = rank_arr[(size_t)b * CAP + e] + (e & (STILE - 1u));  // cross-tile + in-tile
  uint32_t pos = bucket_base[b] + rank;
  uint64_t ub = (myk & 0x8000000000000000ULL) ? (myk ^ 0x8000000000000000ULL) : ~myk;
  double t_ev = __longlong_as_double((long long)ub);
  uint32_t myidx = mym & 0x7FFFFFu;
  uint32_t pix = (myidx >> 2) % HWPIX;
  uint32_t x = pix % WW, y = pix / WW;
  int32_t pval = ((mym >> 23) & 1u) ? -1 : 1;
  long long ti = (long long)t_ev;              // trunc-toward-zero == astype(int64) for t_ev >= 0
  out[pos]              = (int32_t)x;
  out[NSLOTS + pos]     = (int32_t)y;
  out[2 * NSLOTS + pos] = (int32_t)ti;
  out[3 * NSLOTS + pos] = pval;
  out[4 * NSLOTS + pos] = 1;
}

// ---------------- Kernel 5: invalid slots -> tail, original flat order ----------------
__global__ void invalid_scatter(const uint8_t* __restrict__ npol, const uint32_t* __restrict__ pixpre,
                                const uint32_t* __restrict__ chunk_base, const uint32_t* __restrict__ frame_base,
                                int32_t* __restrict__ out) {
  uint32_t s = blockIdx.x * blockDim.x + threadIdx.x;
  if (s >= (uint32_t)NSLOTS) return;
  uint32_t k = (s & 3u) + 1u;
  uint32_t tp = s >> 2;
  uint32_t t = tp / HWPIX;
  uint32_t pix = tp - t * HWPIX;
  uint8_t bb = npol[tp];
  uint32_t n = bb & 7u;
  if (k <= n) return;                          // valid slot, handled by scatter_valid
  uint32_t nvalid_total = frame_base[TT];
  uint32_t vb = frame_base[t] + chunk_base[t * NCHUNK + (pix >> 8)] + pixpre[tp] + min(k - 1u, n);
  uint32_t pos = nvalid_total + (s - vb);
  uint32_t x = pix % WW, y = pix / WW;
  uint32_t pc = (bb >> 3) & 3u;
  int32_t pval = (pc == 1u) ? 1 : ((pc == 2u) ? -1 : 0);
  out[pos]              = (int32_t)x;
  out[NSLOTS + pos]     = (int32_t)y;
  out[2 * NSLOTS + pos] = 0;
  out[3 * NSLOTS + pos] = pval;
  out[4 * NSLOTS + pos] = 0;
}

extern "C" void kernel_launch(void* const* d_in, const int* in_sizes, int n_in,
                              void* d_out, int out_size, void* d_ws, size_t ws_size,
                              hipStream_t stream) {
  const float* images = (const float*)d_in[0];
  int32_t* out = (int32_t*)d_out;

  uint8_t* base = (uint8_t*)d_ws;
  size_t off = 0;
  auto carve = [&](size_t bytes, size_t align) -> void* {
    off = (off + align - 1) & ~(align - 1);
    void* p = base + off; off += bytes; return p;
  };
  uint32_t* bucket_count = (uint32_t*)carve(TT * 4, 256);
  uint32_t* bucket_base  = (uint32_t*)carve((TT + 1) * 4, 256);
  uint32_t* frame_total  = (uint32_t*)carve(TT * 4, 256);
  uint32_t* frame_base   = (uint32_t*)carve((TT + 1) * 4, 256);
  uint8_t*  npol         = (uint8_t*) carve((size_t)TT * HWPIX, 256);
  float*    refs         = (float*)   carve((size_t)TT * HWPIX * 4, 256);
  uint32_t* pixpre       = (uint32_t*)carve((size_t)TT * HWPIX * 4, 256);
  uint32_t* chunk_sum    = (uint32_t*)carve((size_t)TT * NCHUNK * 4, 256);
  uint32_t* chunk_base   = (uint32_t*)carve((size_t)TT * NCHUNK * 4, 256);
  uint64_t* keys         = (uint64_t*)carve((size_t)TT * CAP * 8, 256);
  uint32_t* meta         = (uint32_t*)carve((size_t)TT * CAP * 4, 256);
  uint32_t* rank_arr     = (uint32_t*)carve((size_t)TT * CAP * 4, 256);
  (void)ws_size; (void)out_size; (void)in_sizes; (void)n_in;

  ref_scan<<<(HWPIX + 255) / 256, 256, 0, stream>>>(images, refs, npol, bucket_count);
  dim3 ge(NCHUNK, TT);
  event_emit<<<ge, 256, 0, stream>>>(images, refs, npol, bucket_count, keys, meta, pixpre, chunk_sum);
  chunk_base_scan<<<TT, 256, 0, stream>>>(chunk_sum, chunk_base, frame_total);
  small_scans<<<1, 64, 0, stream>>>(bucket_count, bucket_base, frame_total, frame_base);
  dim3 gs(CAP / STILE, TT);
  sort_tiles<<<gs, 256, 0, stream>>>(keys, meta, bucket_count, rank_arr);
  dim3 gp(64, TT);
  rank_pairs<<<gp, 256, 0, stream>>>(keys, meta, bucket_count, rank_arr);
  dim3 gv(CAP / 256, TT);
  scatter_valid<<<gv, 256, 0, stream>>>(keys, meta, bucket_count, bucket_base, rank_arr, out);
  invalid_scatter<<<(uint32_t)((NSLOTS + 255) / 256), 256, 0, stream>>>(npol, pixpre, chunk_base, frame_base, out);
}